// Round 9
// baseline (235.125 us; speedup 1.0000x reference)
//
#include <hip/hip_runtime.h>
#include <math.h>

// Problem constants: N=100000, S=64, Q=50, P=3
#define N_Q 50
#define N_S 64
#define ROW 150            // floats per pauli word (600 B)
#define THREADS 256        // 4 waves per block
#define RPW 16             // rows per wave (N % 16 == 0)
#define RPB 64             // rows per block
#define EPAD 66            // epilogue LDS row stride (2r+... -> conflict-free)

// ws layout (bytes):
//   [0..4)           done-counter (precompute zeroes it)
//   [64..+12504)     partials double[1563]
//   [12608..+38400)  HT float[150][64]  transposed heads: HT[3q+p][s]
//   [51008..+256)    hrv float[64]
#define WS_CNT_OFF 0
#define WS_PART_OFF 64
#define WS_HT_OFF 12608
#define WS_HRV_OFF 51008

__device__ __forceinline__ float softplus20(float x) {
    float z = x * 20.0f;
    return fmaxf(z, 0.0f) + log1pf(expf(-fabsf(z)));  // stable softplus
}

__global__ void precompute_kernel(const float* __restrict__ heads_param,
                                  const float* __restrict__ hr_param,
                                  float* __restrict__ HT,
                                  float* __restrict__ hrv,
                                  int* __restrict__ cnt) {
    const int tid = threadIdx.x;
    if (blockIdx.x == 0) {
        if (tid == 0) *cnt = 0;             // ws re-poisoned every launch
        if (tid < N_S) {
            float sp = softplus20(hr_param[tid]);
            float tot = sp;
            #pragma unroll
            for (int off = 32; off; off >>= 1) tot += __shfl_xor(tot, off);
            hrv[tid] = (sp / fmaxf(tot, 1e-12f) + 0.001f / (float)N_S) / 1.001f;
        }
    }
    // EXACT reference semantics: h_p = sp_p / max(sum, EPS). When the clamp
    // fires the row does NOT sum to 1 -> all three components stored.
    int idx = blockIdx.x * blockDim.x + tid;
    if (idx < N_S * N_Q) {
        int q = idx >> 6, s = idx & 63;
        const float* hp = heads_param + ((size_t)s * N_Q + q) * 3;
        float sp0 = softplus20(hp[0]);
        float sp1 = softplus20(hp[1]);
        float sp2 = softplus20(hp[2]);
        float denom = fmaxf(sp0 + sp1 + sp2, 1e-12f);
        HT[(3 * q + 0) * N_S + s] = sp0 / denom;   // HT[k][s]: lane=s coalesced
        HT[(3 * q + 1) * N_S + s] = sp1 / denom;
        HT[(3 * q + 2) * N_S + s] = sp2 / denom;
    }
}

// 12 broadcast float2 loads (all lanes same addr -> 1 line req, vmcnt domain)
__device__ __forceinline__ void loadW(float2 (&b)[12], const float2* __restrict__ p) {
    #pragma unroll
    for (int j = 0; j < 12; ++j) b[j] = p[j];
}

// one row x 8 qubits against this lane's s (hv VGPR-resident)
__device__ __forceinline__ float dot8(const float2 (&b)[12], const float (&hv)[24]) {
    float a[24];
    #pragma unroll
    for (int j = 0; j < 12; ++j) { a[2 * j] = b[j].x; a[2 * j + 1] = b[j].y; }
    float d[8];
    #pragma unroll
    for (int q = 0; q < 8; ++q)
        d[q] = fmaf(hv[3 * q + 0], a[3 * q + 0],
               fmaf(hv[3 * q + 1], a[3 * q + 1],
                    hv[3 * q + 2] * a[3 * q + 2]));
    return ((d[0] * d[1]) * (d[2] * d[3])) * ((d[4] * d[5]) * (d[6] * d[7]));
}

__global__ __launch_bounds__(THREADS) void main_kernel(
    const float* __restrict__ A, const float* __restrict__ coeff,
    const float* __restrict__ HT, const float* __restrict__ hrv,
    double* __restrict__ partials, int* __restrict__ cnt,
    float* __restrict__ out, int N) {
    __shared__ float eps[4][RPW * EPAD];   // 16.5 KB transpose-reduce scratch
    __shared__ double redd[4];
    __shared__ int isLast;

    const int tid = threadIdx.x;
    const int lane = tid & 63;
    const int wv = tid >> 6;
    const int wave_id = blockIdx.x * 4 + wv;
    const int rowbase = wave_id * RPW;

    double dsum = 0.0;
    if (rowbase < N) {
        // divergence taint (value 0): keeps A addresses vector-typed so the
        // compiler emits global_load (vmcnt, deep queue), NOT s_load (lgkm(0)
        // drains killed R2/R6/R8).
        const int dv = __shfl((int)blockIdx.x, 0) - (int)blockIdx.x;
        const float* __restrict__ Adv = A + dv;

        float prod[RPW];
        #pragma unroll
        for (int r = 0; r < RPW; ++r) prod[r] = 1.0f;

        // ---- 6 windows of 8 q ----
        for (int w = 0; w < 6; ++w) {
            float hv[24];                              // this lane's H window
            #pragma unroll
            for (int j = 0; j < 24; ++j) hv[j] = HT[(24 * w + j) * N_S + lane];

            const float2* __restrict__ Af2 =
                (const float2*)Adv + 12 * w + (size_t)rowbase * (ROW / 2);

            float2 b0[12], b1[12];
            loadW(b0, Af2);                            // row 0
            #pragma unroll
            for (int r = 0; r < RPW; r += 2) {         // 2-row double buffer
                loadW(b1, Af2 + (size_t)(r + 1) * (ROW / 2));
                prod[r] *= dot8(b0, hv);
                if (r + 2 < RPW) loadW(b0, Af2 + (size_t)(r + 2) * (ROW / 2));
                prod[r + 1] *= dot8(b1, hv);
            }
        }
        // ---- tail: q = 48,49 (floats 144..149) ----
        {
            float hv6[6];
            #pragma unroll
            for (int j = 0; j < 6; ++j) hv6[j] = HT[(144 + j) * N_S + lane];
            const float2* __restrict__ Af2 =
                (const float2*)Adv + 72 + (size_t)rowbase * (ROW / 2);
            #pragma unroll
            for (int r = 0; r < RPW; ++r) {
                float2 t0 = Af2[(size_t)r * 75 + 0];
                float2 t1 = Af2[(size_t)r * 75 + 1];
                float2 t2 = Af2[(size_t)r * 75 + 2];
                float d0 = fmaf(hv6[0], t0.x, fmaf(hv6[1], t0.y, hv6[2] * t1.x));
                float d1 = fmaf(hv6[3], t1.y, fmaf(hv6[4], t2.x, hv6[5] * t2.y));
                prod[r] *= d0 * d1;
            }
        }

        // ---- epilogue: LDS transpose-reduce over s ----
        const float hrw = hrv[lane];
        float* ep = eps[wv];
        #pragma unroll
        for (int r = 0; r < RPW; ++r) ep[r * EPAD + lane] = prod[r] * hrw;
        // per-wave LDS ops are in-order; no barrier needed (wave-private region)
        const int rr = lane & 15, cc = lane >> 4;      // lane -> (row, quarter)
        const float2* erow = (const float2*)(ep + rr * EPAD + cc * 16);
        float cv = 0.0f;
        #pragma unroll
        for (int j = 0; j < 8; ++j) { float2 e = erow[j]; cv += e.x + e.y; }
        cv += __shfl_xor(cv, 16);
        cv += __shfl_xor(cv, 32);                      // full cov of row rr
        if (lane < 16) {
            float c = coeff[rowbase + rr];             // 16-lane coalesced
            dsum = (double)((c * c) / cv);
        }
    }
    // wave-sum dsum -> block partial
    #pragma unroll
    for (int off = 32; off; off >>= 1) dsum += __shfl_down(dsum, off);
    if (lane == 0) redd[wv] = dsum;
    __syncthreads();

    if (tid == 0) {
        partials[blockIdx.x] = redd[0] + redd[1] + redd[2] + redd[3];
        __threadfence();                               // release partial
        int v = atomicAdd(cnt, 1);
        isLast = (v == (int)gridDim.x - 1);
    }
    __syncthreads();

    if (isLast) {                                      // last block: final sum
        __threadfence();                               // acquire
        double s = 0.0;
        for (int i = tid; i < (int)gridDim.x; i += THREADS) s += partials[i];
        #pragma unroll
        for (int off = 32; off; off >>= 1) s += __shfl_down(s, off);
        if (lane == 0) redd[wv] = s;
        __syncthreads();
        if (tid == 0) out[0] = (float)(redd[0] + redd[1] + redd[2] + redd[3]);
    }
}

extern "C" void kernel_launch(void* const* d_in, const int* in_sizes, int n_in,
                              void* d_out, int out_size, void* d_ws, size_t ws_size,
                              hipStream_t stream) {
    const float* A           = (const float*)d_in[0];  // [N, Q, P]
    const float* coeff       = (const float*)d_in[1];  // [N]
    const float* heads_param = (const float*)d_in[2];  // [S, Q, P]
    const float* hr_param    = (const float*)d_in[3];  // [S]
    const int N = in_sizes[1];

    char* ws = (char*)d_ws;
    int*    cnt      = (int*)(ws + WS_CNT_OFF);
    double* partials = (double*)(ws + WS_PART_OFF);
    float*  HT       = (float*)(ws + WS_HT_OFF);
    float*  hrv      = (float*)(ws + WS_HRV_OFF);
    float*  out      = (float*)d_out;

    const int pre_blocks = (N_S * N_Q + THREADS - 1) / THREADS;  // 13
    precompute_kernel<<<pre_blocks, THREADS, 0, stream>>>(heads_param, hr_param,
                                                          HT, hrv, cnt);
    const int nblocks = (N + RPB - 1) / RPB;           // 1563
    main_kernel<<<nblocks, THREADS, 0, stream>>>(A, coeff, HT, hrv,
                                                 partials, cnt, out, N);
}